// Round 3
// baseline (215.787 us; speedup 1.0000x reference)
//
#include <hip/hip_runtime.h>
#include <cstdint>
#include <cstddef>

// Problem constants
#define NCB   8
#define KC    1024
#define SDIM  64
#define LDIM  512          // NCB*SDIM
#define BATCH 8192
#define INV_TAU (1.0f/0.07f)
#define K2E  20.60992915555662f   // log2(e)/TAU
#define DBIAS 256.0f           // dist bias: dist+256 in [174,466) -> positive, 2 binades

typedef __bf16 bf16_t;
typedef bf16_t bf16x8 __attribute__((ext_vector_type(8)));
typedef float  floatx4 __attribute__((ext_vector_type(4)));
typedef int    intx8  __attribute__((ext_vector_type(8)));
typedef unsigned int u32;

__device__ __forceinline__ unsigned short f2bf(float f) {
    union { float f; unsigned int u; } c; c.f = f;
    unsigned int u = c.u;
    u += 0x7fffu + ((u >> 16) & 1u);   // round-to-nearest-even
    return (unsigned short)(u >> 16);
}
__device__ __forceinline__ float bf2f(unsigned short h) {
    union { unsigned int u; float f; } c; c.u = ((unsigned int)h) << 16;
    return c.f;
}
__device__ __forceinline__ float exp2_fast(float x) {
    float r; asm("v_exp_f32 %0, %1" : "=v"(r) : "v"(x)); return r;
}

// ---------------------------------------------------------------------------
// K0: embeddings only (32 blocks): e2 + bf16 hi/lo split + zero accs.
// ---------------------------------------------------------------------------
__global__ __launch_bounds__(256) void
k_pre(const float* __restrict__ emb, float* __restrict__ e2,
      unsigned short* __restrict__ eh, unsigned short* __restrict__ el,
      float* __restrict__ accs) {
    int id = blockIdx.x * 256 + threadIdx.x;   // 0..8191 = n*K+k
    const float4* e4 = (const float4*)(emb + (size_t)id * SDIM);
    ushort4* eh4 = (ushort4*)(eh + (size_t)id * SDIM);
    ushort4* el4 = (ushort4*)(el + (size_t)id * SDIM);
    float s0=0.f,s1=0.f,s2=0.f,s3=0.f;
#pragma unroll
    for (int i=0;i<16;i++){ float4 v=e4[i];
        s0=fmaf(v.x,v.x,s0); s1=fmaf(v.y,v.y,s1);
        s2=fmaf(v.z,v.z,s2); s3=fmaf(v.w,v.w,s3);
        ushort4 h, l;
        h.x=f2bf(v.x); l.x=f2bf(v.x-bf2f(h.x));
        h.y=f2bf(v.y); l.y=f2bf(v.y-bf2f(h.y));
        h.z=f2bf(v.z); l.z=f2bf(v.z-bf2f(h.z));
        h.w=f2bf(v.w); l.w=f2bf(v.w-bf2f(h.w));
        eh4[i]=h; el4[i]=l;
    }
    e2[id] = (s0+s1)+(s2+s3);
    if (id==0){ accs[0]=0.f; accs[1]=0.f; accs[2]=0.f; }
}

// fp64 "relative distance" e2 - 2*z.e (z2 cancels in argmin ordering)
__device__ __forceinline__ double dist64d(const float* __restrict__ e,
                                          const float* __restrict__ zg) {
    double se=0.0, sz=0.0;
#pragma unroll 8
    for (int i=0;i<64;i++){ double ev=(double)e[i];
        se = fma(ev,ev,se); sz = fma(ev,(double)zg[i],sz); }
    return se - 2.0*sz;
}

// ---------------------------------------------------------------------------
// K2: MFMA argmin. R16 restructure (resubmit after infra failure):
// BARRIER-FREE main loop. R15 post-mortem: zeroing bank conflicts + dbuf
// pipeline changed nothing -> bottleneck is lockstep barriers at 2 blocks/CU
// (LDS-capped), not LDS conflicts. eh/el (2 MB) are L2-resident, so B
// fragments are loaded straight global->VGPR each jt; e2 also direct.
// LDS = A (32 KB, swizzled, written once) + mK only => 34 KB,
// launch_bounds(256,3) => 3 blocks/CU (12 waves/CU), and NO __syncthreads
// in the jt loop — waves skew freely to overlap VMEM/MFMA/VALU.
// ---------------------------------------------------------------------------
__global__ __launch_bounds__(256,3) void
k_argmin(const unsigned short* __restrict__ eh, const unsigned short* __restrict__ el,
         const float* __restrict__ e2, const float* __restrict__ z,
         const float* __restrict__ emb, float* __restrict__ out_q,
         float* __restrict__ out_idx, float* __restrict__ accs) {
    __shared__ __align__(16) unsigned short Ah[128*64], Al[128*64];
    __shared__ unsigned int mK[2][128][2];

    const int tid = threadIdx.x;
    const int n   = blockIdx.y;
    const int i0  = blockIdx.x * 128;
    const int wid = tid >> 6, lane = tid & 63;
    const int wm = wid & 1, wn = wid >> 1;
    const int c  = lane & 15, qq = lane >> 4;

    // stage A (resident): read z fp32, split hi/lo in-kernel, swizzled store
#pragma unroll
    for (int s=0;s<8;s++){
        int seg = tid + s*256;           // 2048 segs; 16 float4-segs per row
        int r = seg >> 4, sg = seg & 15;
        float4 v = *(const float4*)(z + (size_t)(i0+r)*LDIM + n*SDIM + sg*4);
        ushort4 h, l;
        h.x=f2bf(v.x); l.x=f2bf(v.x-bf2f(h.x));
        h.y=f2bf(v.y); l.y=f2bf(v.y-bf2f(h.y));
        h.z=f2bf(v.z); l.z=f2bf(v.z-bf2f(h.z));
        h.w=f2bf(v.w); l.w=f2bf(v.w-bf2f(h.w));
        int off = r*64 + ((sg*4) ^ ((r&7)<<3));   // shorts; == byte XOR (r&7)<<4
        *(ushort4*)(&Ah[off]) = h;
        *(ushort4*)(&Al[off]) = l;
    }

    const unsigned short* ehn = eh + (size_t)n*KC*SDIM;
    const unsigned short* eln = el + (size_t)n*KC*SDIM;
    const float* e2n = e2 + n*KC;

    unsigned int k1[16], k2[16];
#pragma unroll
    for (int j=0;j<16;j++){ k1[j]=0xFFFFFFFFu; k2[j]=0xFFFFFFFFu; }

    __syncthreads();          // A published; the ONLY pre-epilogue barrier

    for (int jt=0; jt<16; jt++){
        const int j0 = jt*64;

        // B fragments + e2, straight from global (L2-resident, no barriers)
        bf16x8 bh[2][2], bl[2][2];
        float e2v[2];
#pragma unroll
        for (int nt=0;nt<2;nt++){
            const int row = j0 + wn*32 + nt*16 + c;
            const size_t rb = (size_t)row * SDIM;
            e2v[nt] = e2n[row] + DBIAS;
#pragma unroll
            for (int t=0;t<2;t++){
                bh[nt][t] = *(const bf16x8*)(ehn + rb + t*32 + qq*8);
                bl[nt][t] = *(const bf16x8*)(eln + rb + t*32 + qq*8);
            }
        }

        floatx4 acc[4][2];
#pragma unroll
        for (int mt=0;mt<4;mt++){
            acc[mt][0]=(floatx4){0.f,0.f,0.f,0.f};
            acc[mt][1]=(floatx4){0.f,0.f,0.f,0.f};
        }

#pragma unroll
        for (int t=0;t<2;t++){
            const int axo = (t*32 + qq*8) ^ ((c&7)<<3);   // shorts
            bf16x8 ah[4], alo[4];
#pragma unroll
            for (int mt=0;mt<4;mt++){
                int ro = (wm*64 + mt*16 + c)*64 + axo;
                ah[mt]  = *(const bf16x8*)(&Ah[ro]);
                alo[mt] = *(const bf16x8*)(&Al[ro]);
            }
#pragma unroll
            for (int mt=0;mt<4;mt++)
#pragma unroll
                for (int nt=0;nt<2;nt++){
                    acc[mt][nt] = __builtin_amdgcn_mfma_f32_16x16x32_bf16(ah[mt],  bh[nt][t], acc[mt][nt], 0,0,0);
                    acc[mt][nt] = __builtin_amdgcn_mfma_f32_16x16x32_bf16(ah[mt],  bl[nt][t], acc[mt][nt], 0,0,0);
                    acc[mt][nt] = __builtin_amdgcn_mfma_f32_16x16x32_bf16(alo[mt], bh[nt][t], acc[mt][nt], 0,0,0);
                }
        }

        // biased dist -> packed key -> branchless top-2 (min + med3)
#pragma unroll
        for (int nt=0;nt<2;nt++){
            const int colb = wn*32 + nt*16 + c;
            unsigned int kidx = (unsigned int)(j0 + colb);
#pragma unroll
            for (int mt=0;mt<4;mt++)
#pragma unroll
                for (int reg=0;reg<4;reg++){
                    float d = fmaf(-2.0f, acc[mt][nt][reg], e2v[nt]);
                    unsigned int key = (__float_as_uint(d) & 0xFFFFFC00u) | kidx;
                    int s = mt*4+reg;
                    unsigned int o1 = k1[s], o2 = k2[s];
                    unsigned int nk2;
                    asm("v_med3_u32 %0, %1, %2, %3" : "=v"(nk2) : "v"(o1), "v"(o2), "v"(key));
                    k2[s] = nk2;                 // 2nd-smallest of {k1,k2,key}
                    k1[s] = min(o1, key);
                }
        }
    }

    // butterfly top-2 merge across the 16 col-lanes
#pragma unroll
    for (int off=1; off<16; off<<=1){
#pragma unroll
        for (int s=0;s<16;s++){
            unsigned int o1 = __shfl_xor(k1[s], off);
            unsigned int o2 = __shfl_xor(k2[s], off);
            unsigned int n1 = min(k1[s], o1);
            k2[s] = min( max(k1[s], o1), min(k2[s], o2) );
            k1[s] = n1;
        }
    }
    if (c == 0){
#pragma unroll
        for (int s=0;s<16;s++){
            int row = wm*64 + (s>>2)*16 + qq*4 + (s&3);
            mK[wn][row][0] = k1[s]; mK[wn][row][1] = k2[s];
        }
    }
    __syncthreads();

    if (tid < 128){
        int b = i0 + tid;
        unsigned int a1 = mK[0][tid][0], a2 = mK[0][tid][1];
        unsigned int c1 = mK[1][tid][0], c2 = mK[1][tid][1];
        unsigned int f1 = min(a1, c1);
        unsigned int f2 = min( max(a1, c1), min(a2, c2) );
        int ii1 = (int)(f1 & 0x3FFu);
        int ii2 = (int)(f2 & 0x3FFu);
        float d1q = __uint_as_float(f1 & 0xFFFFFC00u);
        float d2q = __uint_as_float(f2 & 0xFFFFFC00u);

        const float* eb = emb + (size_t)n*KC*SDIM;
        const float* zg = z + (size_t)b*LDIM + n*SDIM;
        if (d2q - d1q < 0.08f) {   // window covers quantization (0.031) + bf16 err
            double d1 = dist64d(eb + (size_t)ii1*SDIM, zg);
            double d2 = dist64d(eb + (size_t)ii2*SDIM, zg);
            if (d2 < d1 || (d2 == d1 && ii2 < ii1)) ii1 = ii2;
        }

        const float4* q4 = (const float4*)(eb + (size_t)ii1*SDIM);
        const float4* z4 = (const float4*)zg;
        float4* oq = (float4*)(out_q + (size_t)b*LDIM + n*SDIM);
        float cs = 0.f;
#pragma unroll
        for (int i=0;i<16;i++){
            float4 v = q4[i]; float4 zv = z4[i];
            oq[i] = v;
            float d0=v.x-zv.x, d1=v.y-zv.y, d2=v.z-zv.z, d3=v.w-zv.w;
            cs += d0*d0 + d1*d1 + d2*d2 + d3*d3;
        }
        out_idx[b*NCB + n] = (float)ii1;

        for (int off=32; off; off>>=1) cs += __shfl_down(cs, off);
        if ((tid & 63)==0) atomicAdd(&accs[0], cs);
    }
}

// ---------------------------------------------------------------------------
// K3: per-row L2 norms; write normalized FP8 (e4m3) copies + diag.
// ---------------------------------------------------------------------------
__global__ __launch_bounds__(256) void
k_norm(const float* __restrict__ z, const float* __restrict__ q,
       unsigned char* __restrict__ zn8, unsigned char* __restrict__ qn8,
       float* __restrict__ diag) {
    const int b = blockIdx.x, tid = threadIdx.x;
    const size_t base = (size_t)b*LDIM;
    float2 zv = ((const float2*)(z+base))[tid];
    float2 qv = ((const float2*)(q+base))[tid];
    float sz = zv.x*zv.x + zv.y*zv.y;
    float sq = qv.x*qv.x + qv.y*qv.y;
    float sqz= qv.x*zv.x + qv.y*zv.y;
    for (int off=32; off; off>>=1){
        sz+=__shfl_down(sz,off); sq+=__shfl_down(sq,off); sqz+=__shfl_down(sqz,off);
    }
    __shared__ float red[3][4];
    __shared__ float bc[2];
    int w = tid>>6;
    if ((tid&63)==0){ red[0][w]=sz; red[1][w]=sq; red[2][w]=sqz; }
    __syncthreads();
    if (tid==0){
        float tz = red[0][0]+red[0][1]+red[0][2]+red[0][3];
        float tq = red[1][0]+red[1][1]+red[1][2]+red[1][3];
        float tz_q = red[2][0]+red[2][1]+red[2][2]+red[2][3];
        float inz = 1.0f/fmaxf(sqrtf(tz), 1e-12f);
        float inq = 1.0f/fmaxf(sqrtf(tq), 1e-12f);
        bc[0]=inz; bc[1]=inq;
        diag[b] = tz_q*inz*inq*INV_TAU;
    }
    __syncthreads();
    float inz=bc[0], inq=bc[1];
    int pz = __builtin_amdgcn_cvt_pk_fp8_f32(zv.x*inz, zv.y*inz, 0, false);
    int pq = __builtin_amdgcn_cvt_pk_fp8_f32(qv.x*inq, qv.y*inq, 0, false);
    ((unsigned short*)(zn8+base))[tid] = (unsigned short)(pz & 0xffff);
    ((unsigned short*)(qn8+base))[tid] = (unsigned short)(pq & 0xffff);
}

// ---------------------------------------------------------------------------
// K4: logsumexp of logits = qn8 · zn8^T / TAU via MX-scaled fp8 MFMA
// 16x16x128 (scales=1.0). R16 restructure: ZERO LDS, ZERO barriers.
// A (q rows) resident in registers (128 VGPRs, loaded once); B fragments
// loaded straight global->VGPR per 64-col tile (zn8 is 4 MB, L2-resident;
// the frag pattern touches full 64B lines). No staging, no syncthreads —
// the 2 blocks/CU worth of waves skew freely.
// ---------------------------------------------------------------------------
__global__ __launch_bounds__(256,2) void
k_logits(const unsigned char* __restrict__ qn8, const unsigned char* __restrict__ zn8,
         float* __restrict__ Spart) {
    const int tid  = threadIdx.x;
    const int i0   = blockIdx.x * 128;
    const int chnk = blockIdx.y;           // 1024 cols each
    const int wid  = tid >> 6, lane = tid & 63;
    const int wm = wid & 1, wn = wid >> 1;
    const int c  = lane & 15, qq = lane >> 4;

    // ---- A resident in regs: 4 mt x 4 kc fragments (rows wm*64+mt*16+c)
    intx8 af[4][4];
#pragma unroll
    for (int mt=0;mt<4;mt++){
        const unsigned char* ap = qn8 + (size_t)(i0 + wm*64 + mt*16 + c)*LDIM + qq*32;
#pragma unroll
        for (int kc=0;kc<4;kc++){
            union { intx8 v; uint4 h[2]; } u;
            u.h[0] = *(const uint4*)(ap + kc*128);
            u.h[1] = *(const uint4*)(ap + kc*128 + 16);
            af[mt][kc] = u.v;
        }
    }

    float S[16];
#pragma unroll
    for (int i=0;i<16;i++) S[i] = 0.f;

    for (int jt=0;jt<16;jt++){
        const int j0 = chnk*1024 + jt*64;

        // B fragments straight from global (L2-resident)
        const unsigned char* bp = zn8 + (size_t)(j0 + wn*32 + c)*LDIM + qq*32;
        intx8 bfr[2][4];
#pragma unroll
        for (int nt=0;nt<2;nt++)
#pragma unroll
            for (int kc=0;kc<4;kc++){
                union { intx8 v; uint4 h[2]; } u;
                u.h[0] = *(const uint4*)(bp + (size_t)nt*16*LDIM + kc*128);
                u.h[1] = *(const uint4*)(bp + (size_t)nt*16*LDIM + kc*128 + 16);
                bfr[nt][kc] = u.v;
            }

        floatx4 acc[4][2];
#pragma unroll
        for (int mt=0;mt<4;mt++){
            acc[mt][0]=(floatx4){0.f,0.f,0.f,0.f};
            acc[mt][1]=(floatx4){0.f,0.f,0.f,0.f};
        }

#pragma unroll
        for (int kc=0;kc<4;kc++)
#pragma unroll
            for (int mt=0;mt<4;mt++)
#pragma unroll
                for (int nt=0;nt<2;nt++)
                    acc[mt][nt] = __builtin_amdgcn_mfma_scale_f32_16x16x128_f8f6f4(
                        af[mt][kc], bfr[nt][kc], acc[mt][nt],
                        0, 0,        // cbsz=FP8(e4m3), blgp=FP8(e4m3)
                        0, 127,      // scale_a opsel, scale_a (e8m0 1.0)
                        0, 127);     // scale_b opsel, scale_b

        // S[row-slot] += sum_nt 2^((dot-1)*K2E)
#pragma unroll
        for (int mt=0;mt<4;mt++)
#pragma unroll
            for (int reg=0;reg<4;reg++){
                float e0 = exp2_fast(fmaf(acc[mt][0][reg], K2E, -K2E));
                float e1 = exp2_fast(fmaf(acc[mt][1][reg], K2E, -K2E));
                S[mt*4+reg] += e0 + e1;
            }
    }

    // reduce over the 16 col-lanes (disjoint cols, same rows)
#pragma unroll
    for (int off=1; off<16; off<<=1)
#pragma unroll
        for (int s=0;s<16;s++) S[s] += __shfl_xor(S[s], off);

    if (c == 0){
        const int p = chnk*2 + wn;             // 16 partial slots
#pragma unroll
        for (int mt=0;mt<4;mt++)
#pragma unroll
            for (int reg=0;reg<4;reg++){
                int row = i0 + wm*64 + mt*16 + qq*4 + reg;
                Spart[p*BATCH + row] = S[mt*4+reg];
            }
    }
}

// ---------------------------------------------------------------------------
// K5: combine 16 partials/row -> LSE - diag, reduce to accs[1]; the LAST
// block (device-scope counter accs[2]) also writes the two output scalars.
// ---------------------------------------------------------------------------
__global__ __launch_bounds__(256) void
k_finalize(const float* __restrict__ Spart, const float* __restrict__ diag,
           float* __restrict__ accs, float* __restrict__ out_s) {
    int r = blockIdx.x*256 + threadIdx.x;
    float Ssum = 0.f;
#pragma unroll
    for (int p=0;p<16;p++) Ssum += Spart[p*BATCH + r];
    float val = INV_TAU + logf(Ssum) - diag[r];
    for (int off=32; off; off>>=1) val += __shfl_down(val, off);
    if ((threadIdx.x & 63)==0) atomicAdd(&accs[1], val);
    __syncthreads();                       // drains this block's atomics
    if (threadIdx.x == 0){
        __threadfence();
        unsigned int old = __float_as_uint(atomicAdd(&accs[2], 1.0f));
        if (old == __float_as_uint(31.0f)) {   // 32nd (last) block
            __threadfence();
            float a0 = atomicAdd(&accs[0], 0.0f);
            float a1 = atomicAdd(&accs[1], 0.0f);
            out_s[0] = 2.0f*a0 / (float)((size_t)BATCH*LDIM);   // commit+embed
            out_s[1] = a1 / (float)BATCH;                       // contrastive
        }
    }
}

// ---------------------------------------------------------------------------
extern "C" void kernel_launch(void* const* d_in, const int* in_sizes, int n_in,
                              void* d_out, int out_size, void* d_ws, size_t ws_size,
                              hipStream_t stream) {
    const float* z   = (const float*)d_in[0];   // (B, L)
    const float* emb = (const float*)d_in[1];   // (NC, K, SD)
    float* out = (float*)d_out;
    float* out_q       = out;                   // B*L = 4194304
    float* out_scalars = out + 4194304;         // [commit, contrastive]
    float* out_idx     = out + 4194306;         // B*NC as float

    // ws layout (float offsets); ~11 MB total
    float* wsf   = (float*)d_ws;
    float* e2    = wsf;                         // 8192
    float* accs  = wsf + 8192;                  // [commit, contrastive, counter]
    float* diag  = wsf + 8704;                  // 8192
    float* Spart = wsf + 16896;                 // 16 slots used (32 reserved)
    unsigned char* qn8 = (unsigned char*)(Spart + 32*BATCH);   // B*L fp8 (4 MB)
    unsigned char* zn8 = qn8 + (size_t)BATCH*LDIM;             // B*L fp8 (4 MB)
    unsigned short* eh = (unsigned short*)(zn8 + (size_t)BATCH*LDIM); // NC*K*SD bf16
    unsigned short* el = eh + (size_t)NCB*KC*SDIM;             // NC*K*SD bf16

    k_pre    <<<32,          256, 0, stream>>>(emb, e2, eh, el, accs);
    k_argmin <<<dim3(64,8),  256, 0, stream>>>(eh, el, e2, z, emb,
                                               out_q, out_idx, accs);
    k_norm   <<<BATCH,       256, 0, stream>>>(z, out_q, zn8, qn8, diag);
    k_logits <<<dim3(64,8),  256, 0, stream>>>(qn8, zn8, Spart);
    k_finalize<<<32,         256, 0, stream>>>(Spart, diag, accs, out_scalars);
}

// Round 4
// 184.279 us; speedup vs baseline: 1.1710x; 1.1710x over previous
//
#include <hip/hip_runtime.h>
#include <cstdint>
#include <cstddef>

// Problem constants
#define NCB   8
#define KC    1024
#define SDIM  64
#define LDIM  512          // NCB*SDIM
#define BATCH 8192
#define INV_TAU (1.0f/0.07f)
#define K2E  20.60992915555662f   // log2(e)/TAU
#define DBIAS 256.0f           // dist bias: dist+256 in [174,466) -> positive, 2 binades

typedef __bf16 bf16_t;
typedef bf16_t bf16x8 __attribute__((ext_vector_type(8)));
typedef float  floatx4 __attribute__((ext_vector_type(4)));
typedef int    intx8  __attribute__((ext_vector_type(8)));
typedef unsigned int u32;

__device__ __forceinline__ unsigned short f2bf(float f) {
    union { float f; unsigned int u; } c; c.f = f;
    unsigned int u = c.u;
    u += 0x7fffu + ((u >> 16) & 1u);   // round-to-nearest-even
    return (unsigned short)(u >> 16);
}
__device__ __forceinline__ float bf2f(unsigned short h) {
    union { unsigned int u; float f; } c; c.u = ((unsigned int)h) << 16;
    return c.f;
}
__device__ __forceinline__ float exp2_fast(float x) {
    float r; asm("v_exp_f32 %0, %1" : "=v"(r) : "v"(x)); return r;
}
// async global->LDS DMA, 16B/lane. LDS dest = wave-uniform base + lane*16 (linear).
__device__ __forceinline__ void gll16(const void* g, void* l) {
    __builtin_amdgcn_global_load_lds(
        (const __attribute__((address_space(1))) u32*)g,
        (__attribute__((address_space(3))) u32*)l,
        16, 0, 0);
}

// ---------------------------------------------------------------------------
// K0: embeddings only (32 blocks): e2 + bf16 hi/lo split + zero accs.
// ---------------------------------------------------------------------------
__global__ __launch_bounds__(256) void
k_pre(const float* __restrict__ emb, float* __restrict__ e2,
      unsigned short* __restrict__ eh, unsigned short* __restrict__ el,
      float* __restrict__ accs) {
    int id = blockIdx.x * 256 + threadIdx.x;   // 0..8191 = n*K+k
    const float4* e4 = (const float4*)(emb + (size_t)id * SDIM);
    ushort4* eh4 = (ushort4*)(eh + (size_t)id * SDIM);
    ushort4* el4 = (ushort4*)(el + (size_t)id * SDIM);
    float s0=0.f,s1=0.f,s2=0.f,s3=0.f;
#pragma unroll
    for (int i=0;i<16;i++){ float4 v=e4[i];
        s0=fmaf(v.x,v.x,s0); s1=fmaf(v.y,v.y,s1);
        s2=fmaf(v.z,v.z,s2); s3=fmaf(v.w,v.w,s3);
        ushort4 h, l;
        h.x=f2bf(v.x); l.x=f2bf(v.x-bf2f(h.x));
        h.y=f2bf(v.y); l.y=f2bf(v.y-bf2f(h.y));
        h.z=f2bf(v.z); l.z=f2bf(v.z-bf2f(h.z));
        h.w=f2bf(v.w); l.w=f2bf(v.w-bf2f(h.w));
        eh4[i]=h; el4[i]=l;
    }
    e2[id] = (s0+s1)+(s2+s3);
    if (id==0){ accs[0]=0.f; accs[1]=0.f; accs[2]=0.f; }
}

// fp64 "relative distance" e2 - 2*z.e (z2 cancels in argmin ordering)
__device__ __forceinline__ double dist64d(const float* __restrict__ e,
                                          const float* __restrict__ zg) {
    double se=0.0, sz=0.0;
#pragma unroll 8
    for (int i=0;i<64;i++){ double ev=(double)e[i];
        se = fma(ev,ev,se); sz = fma(ev,(double)zg[i],sz); }
    return se - 2.0*sz;
}

// ---------------------------------------------------------------------------
// K2: MFMA argmin. R17: A-fragments in REGISTERS (64 VGPR, loaded once from
// z with in-reg hi/lo split — removes 32 KB LDS + 16 ds_reads/jt); B staged
// via gll double-buffer (R1-verified geometry: pre-swizzled source, linear
// LDS, XOR'd frag reads), ONE barrier/jt. LDS 34 KB + VGPR<=168 =>
// launch_bounds(256,3) = 3 blocks/CU (12 waves/CU, was 8). R3 post-mortem:
// direct global B frags exposed L2 latency (scattered 16B, no pipeline) —
// staging must stay coalesced+LDS; occupancy is the lever.
// ---------------------------------------------------------------------------
__global__ __launch_bounds__(256,3) void
k_argmin(const unsigned short* __restrict__ eh, const unsigned short* __restrict__ el,
         const float* __restrict__ e2, const float* __restrict__ z,
         const float* __restrict__ emb, float* __restrict__ out_q,
         float* __restrict__ out_idx, float* __restrict__ accs) {
    __shared__ __align__(16) unsigned short Bh[2][64*64], Bl[2][64*64];
    __shared__ unsigned int mK[2][128][2];

    const int tid = threadIdx.x;
    const int n   = blockIdx.y;
    const int i0  = blockIdx.x * 128;
    const int wid = tid >> 6, lane = tid & 63;
    const int wm = wid & 1, wn = wid >> 1;
    const int c  = lane & 15, qq = lane >> 4;

    const unsigned char* ehb = (const unsigned char*)(eh + (size_t)n*KC*SDIM);
    const unsigned char* elb = (const unsigned char*)(el + (size_t)n*KC*SDIM);
    const float* e2n = e2 + n*KC;

    // gll lane geometry: 8 rows x 128B per wave-instr; source pre-swizzled
    const int brow = lane >> 3;                       // row-in-8
    const int bchk = ((lane & 7)*16) ^ (brow << 4);   // swizzled byte in row

    auto stageB = [&](int buf, int j0){
#pragma unroll
        for (int s=0;s<2;s++){
            int r0 = wid*16 + s*8;                    // multiple of 8
            size_t go = (size_t)(j0 + r0 + brow)*128 + bchk;
            gll16(ehb + go, &Bh[buf][r0*64]);
            gll16(elb + go, &Bl[buf][r0*64]);
        }
    };

    stageB(0, 0);   // async; drained by the pre-loop barrier

    // ---- A fragments in registers: rows wm*64+mt*16+c, k-bytes t*32+qq*8
    // (loaded once, scattered reads amortized over the whole kernel)
    bf16x8 ah[4][2], al[4][2];
#pragma unroll
    for (int mt=0;mt<4;mt++)
#pragma unroll
        for (int t=0;t<2;t++){
            const float* zr = z + (size_t)(i0 + wm*64 + mt*16 + c)*LDIM
                                + n*SDIM + t*32 + qq*8;
            float4 v0 = *(const float4*)(zr);
            float4 v1 = *(const float4*)(zr + 4);
            ushort4 h0, l0, h1, l1;
            h0.x=f2bf(v0.x); l0.x=f2bf(v0.x-bf2f(h0.x));
            h0.y=f2bf(v0.y); l0.y=f2bf(v0.y-bf2f(h0.y));
            h0.z=f2bf(v0.z); l0.z=f2bf(v0.z-bf2f(h0.z));
            h0.w=f2bf(v0.w); l0.w=f2bf(v0.w-bf2f(h0.w));
            h1.x=f2bf(v1.x); l1.x=f2bf(v1.x-bf2f(h1.x));
            h1.y=f2bf(v1.y); l1.y=f2bf(v1.y-bf2f(h1.y));
            h1.z=f2bf(v1.z); l1.z=f2bf(v1.z-bf2f(h1.z));
            h1.w=f2bf(v1.w); l1.w=f2bf(v1.w-bf2f(h1.w));
            union { bf16x8 v; ushort4 u[2]; } uh, ul;
            uh.u[0]=h0; uh.u[1]=h1; ul.u[0]=l0; ul.u[1]=l1;
            ah[mt][t]=uh.v; al[mt][t]=ul.v;
        }

    unsigned int k1[16], k2[16];
#pragma unroll
    for (int j=0;j<16;j++){ k1[j]=0xFFFFFFFFu; k2[j]=0xFFFFFFFFu; }

    __syncthreads();          // drains stageB(0) (implicit vmcnt0) + publishes

    for (int jt=0; jt<16; jt++){
        const int cur = jt & 1, nxt = cur ^ 1;
        const int j0 = jt*64;
        if (jt < 15) stageB(nxt, j0 + 64);    // async prefetch next tile

        float e2v[2];
#pragma unroll
        for (int nt=0;nt<2;nt++)
            e2v[nt] = e2n[j0 + wn*32 + nt*16 + c] + DBIAS;

        floatx4 acc[4][2];
#pragma unroll
        for (int mt=0;mt<4;mt++){
            acc[mt][0]=(floatx4){0.f,0.f,0.f,0.f};
            acc[mt][1]=(floatx4){0.f,0.f,0.f,0.f};
        }

#pragma unroll
        for (int t=0;t<2;t++){
            const int axo = (t*32 + qq*8) ^ ((c&7)<<3);   // shorts
            bf16x8 bh[2], bl[2];
#pragma unroll
            for (int nt=0;nt<2;nt++){
                int ro = (wn*32 + nt*16 + c)*64 + axo;
                bh[nt] = *(const bf16x8*)(&Bh[cur][ro]);
                bl[nt] = *(const bf16x8*)(&Bl[cur][ro]);
            }
#pragma unroll
            for (int mt=0;mt<4;mt++)
#pragma unroll
                for (int nt=0;nt<2;nt++){
                    acc[mt][nt] = __builtin_amdgcn_mfma_f32_16x16x32_bf16(ah[mt][t], bh[nt], acc[mt][nt], 0,0,0);
                    acc[mt][nt] = __builtin_amdgcn_mfma_f32_16x16x32_bf16(ah[mt][t], bl[nt], acc[mt][nt], 0,0,0);
                    acc[mt][nt] = __builtin_amdgcn_mfma_f32_16x16x32_bf16(al[mt][t], bh[nt], acc[mt][nt], 0,0,0);
                }
        }

        // biased dist -> packed key -> branchless top-2 (min + med3)
#pragma unroll
        for (int nt=0;nt<2;nt++){
            const int colb = wn*32 + nt*16 + c;
            unsigned int kidx = (unsigned int)(j0 + colb);
#pragma unroll
            for (int mt=0;mt<4;mt++)
#pragma unroll
                for (int reg=0;reg<4;reg++){
                    float d = fmaf(-2.0f, acc[mt][nt][reg], e2v[nt]);
                    unsigned int key = (__float_as_uint(d) & 0xFFFFFC00u) | kidx;
                    int s = mt*4+reg;
                    unsigned int o1 = k1[s], o2 = k2[s];
                    unsigned int nk2;
                    asm("v_med3_u32 %0, %1, %2, %3" : "=v"(nk2) : "v"(o1), "v"(o2), "v"(key));
                    k2[s] = nk2;                 // 2nd-smallest of {k1,k2,key}
                    k1[s] = min(o1, key);
                }
        }
        __syncthreads();   // drains gll prefetch (vmcnt0), publishes buf nxt
    }

    // butterfly top-2 merge across the 16 col-lanes
#pragma unroll
    for (int off=1; off<16; off<<=1){
#pragma unroll
        for (int s=0;s<16;s++){
            unsigned int o1 = __shfl_xor(k1[s], off);
            unsigned int o2 = __shfl_xor(k2[s], off);
            unsigned int n1 = min(k1[s], o1);
            k2[s] = min( max(k1[s], o1), min(k2[s], o2) );
            k1[s] = n1;
        }
    }
    if (c == 0){
#pragma unroll
        for (int s=0;s<16;s++){
            int row = wm*64 + (s>>2)*16 + qq*4 + (s&3);
            mK[wn][row][0] = k1[s]; mK[wn][row][1] = k2[s];
        }
    }
    __syncthreads();

    if (tid < 128){
        int b = i0 + tid;
        unsigned int a1 = mK[0][tid][0], a2 = mK[0][tid][1];
        unsigned int c1 = mK[1][tid][0], c2 = mK[1][tid][1];
        unsigned int f1 = min(a1, c1);
        unsigned int f2 = min( max(a1, c1), min(a2, c2) );
        int ii1 = (int)(f1 & 0x3FFu);
        int ii2 = (int)(f2 & 0x3FFu);
        float d1q = __uint_as_float(f1 & 0xFFFFFC00u);
        float d2q = __uint_as_float(f2 & 0xFFFFFC00u);

        const float* eb = emb + (size_t)n*KC*SDIM;
        const float* zg = z + (size_t)b*LDIM + n*SDIM;
        if (d2q - d1q < 0.08f) {   // window covers quantization (0.031) + bf16 err
            double d1 = dist64d(eb + (size_t)ii1*SDIM, zg);
            double d2 = dist64d(eb + (size_t)ii2*SDIM, zg);
            if (d2 < d1 || (d2 == d1 && ii2 < ii1)) ii1 = ii2;
        }

        const float4* q4 = (const float4*)(eb + (size_t)ii1*SDIM);
        const float4* z4 = (const float4*)zg;
        float4* oq = (float4*)(out_q + (size_t)b*LDIM + n*SDIM);
        float cs = 0.f;
#pragma unroll
        for (int i=0;i<16;i++){
            float4 v = q4[i]; float4 zv = z4[i];
            oq[i] = v;
            float d0=v.x-zv.x, d1=v.y-zv.y, d2=v.z-zv.z, d3=v.w-zv.w;
            cs += d0*d0 + d1*d1 + d2*d2 + d3*d3;
        }
        out_idx[b*NCB + n] = (float)ii1;

        for (int off=32; off; off>>=1) cs += __shfl_down(cs, off);
        if ((tid & 63)==0) atomicAdd(&accs[0], cs);
    }
}

// ---------------------------------------------------------------------------
// K3: per-row L2 norms; write normalized FP8 (e4m3) copies + diag.
// ---------------------------------------------------------------------------
__global__ __launch_bounds__(256) void
k_norm(const float* __restrict__ z, const float* __restrict__ q,
       unsigned char* __restrict__ zn8, unsigned char* __restrict__ qn8,
       float* __restrict__ diag) {
    const int b = blockIdx.x, tid = threadIdx.x;
    const size_t base = (size_t)b*LDIM;
    float2 zv = ((const float2*)(z+base))[tid];
    float2 qv = ((const float2*)(q+base))[tid];
    float sz = zv.x*zv.x + zv.y*zv.y;
    float sq = qv.x*qv.x + qv.y*qv.y;
    float sqz= qv.x*zv.x + qv.y*zv.y;
    for (int off=32; off; off>>=1){
        sz+=__shfl_down(sz,off); sq+=__shfl_down(sq,off); sqz+=__shfl_down(sqz,off);
    }
    __shared__ float red[3][4];
    __shared__ float bc[2];
    int w = tid>>6;
    if ((tid&63)==0){ red[0][w]=sz; red[1][w]=sq; red[2][w]=sqz; }
    __syncthreads();
    if (tid==0){
        float tz = red[0][0]+red[0][1]+red[0][2]+red[0][3];
        float tq = red[1][0]+red[1][1]+red[1][2]+red[1][3];
        float tz_q = red[2][0]+red[2][1]+red[2][2]+red[2][3];
        float inz = 1.0f/fmaxf(sqrtf(tz), 1e-12f);
        float inq = 1.0f/fmaxf(sqrtf(tq), 1e-12f);
        bc[0]=inz; bc[1]=inq;
        diag[b] = tz_q*inz*inq*INV_TAU;
    }
    __syncthreads();
    float inz=bc[0], inq=bc[1];
    int pz = __builtin_amdgcn_cvt_pk_fp8_f32(zv.x*inz, zv.y*inz, 0, false);
    int pq = __builtin_amdgcn_cvt_pk_fp8_f32(qv.x*inq, qv.y*inq, 0, false);
    ((unsigned short*)(zn8+base))[tid] = (unsigned short)(pz & 0xffff);
    ((unsigned short*)(qn8+base))[tid] = (unsigned short)(pq & 0xffff);
}

// ---------------------------------------------------------------------------
// K4: logsumexp of logits = qn8 · zn8^T / TAU via MX-scaled fp8 MFMA
// 16x16x128 (scales=1.0). R17 geometry: 512 threads / 8 waves per block
// (4 m-groups x 2 n-groups) so the per-wave A-fragment state is af[2][4]
// = 64 VGPR (R3's af[4][4]=128 exceeded budget -> compiler rematerialized
// it from global every jt; VGPR_Count=108 was the tell). Total regs ~115
// <= 128 cap => launch_bounds(512,4) = 2 blocks/CU = 16 waves/CU
// (4 waves/SIMD, 2x the old occupancy). B staged via gll double-buffer
// (pre-swizzled source, linear LDS), ONE barrier per 64-col tile.
// ---------------------------------------------------------------------------
__global__ __launch_bounds__(512,4) void
k_logits(const unsigned char* __restrict__ qn8, const unsigned char* __restrict__ zn8,
         float* __restrict__ Spart) {
    __shared__ __align__(16) unsigned char Bs[2][64*512];
    const int tid  = threadIdx.x;
    const int i0   = blockIdx.x * 128;
    const int chnk = blockIdx.y;           // 1024 cols each
    const int wid  = tid >> 6, lane = tid & 63;
    const int wm = wid & 3, wn = wid >> 2;  // 4 m-groups x 2 n-groups
    const int c  = lane & 15, qq = lane >> 4;

    // gll lane geometry: 2 rows x 512B per wave-instr; source pre-swizzled
    const int brow  = lane >> 5;
    const int bchk0 = (lane & 31) * 16;

    auto stageB = [&](int buf, int j0){
#pragma unroll
        for (int s=0;s<4;s++){
            int r0  = wid*8 + s*2;
            int row = r0 + brow;
            gll16(zn8 + (size_t)(j0+row)*LDIM + (bchk0 ^ ((row&7)<<4)),
                  &Bs[buf][r0*512]);
        }
    };

    stageB(0, chnk*1024);   // async; drained by the pre-loop barrier

    // ---- A resident in regs: 2 mt x 4 kc fragments (rows i0+wm*32+mt*16+c)
    intx8 af[2][4];
#pragma unroll
    for (int mt=0;mt<2;mt++){
        const unsigned char* ap = qn8 + (size_t)(i0 + wm*32 + mt*16 + c)*LDIM + qq*32;
#pragma unroll
        for (int kc=0;kc<4;kc++){
            union { intx8 v; uint4 h[2]; } u;
            u.h[0] = *(const uint4*)(ap + kc*128);
            u.h[1] = *(const uint4*)(ap + kc*128 + 16);
            af[mt][kc] = u.v;
        }
    }

    float S[8];
#pragma unroll
    for (int i=0;i<8;i++) S[i] = 0.f;

    __syncthreads();        // drains stageB(0), publishes buf 0

    for (int jt=0;jt<16;jt++){
        const int cur = jt & 1;
        const int j0 = chnk*1024 + jt*64;
        if (jt < 15) stageB(cur^1, j0 + 64);   // async prefetch next tile

        floatx4 acc[2][2];
#pragma unroll
        for (int mt=0;mt<2;mt++){
            acc[mt][0]=(floatx4){0.f,0.f,0.f,0.f};
            acc[mt][1]=(floatx4){0.f,0.f,0.f,0.f};
        }

#pragma unroll
        for (int kc=0;kc<4;kc++){
            intx8 bfr[2];
#pragma unroll
            for (int nt=0;nt<2;nt++){
                const int rb = wn*32 + nt*16 + c;
                const unsigned char* p = &Bs[cur][rb*512];
                const int o = kc*128 + qq*32;
                const int x = (rb&7)<<4;       // == (c&7)<<4
                union { intx8 v; uint4 h[2]; } u;
                u.h[0] = *(const uint4*)(p + (o ^ x));
                u.h[1] = *(const uint4*)(p + ((o + 16) ^ x));
                bfr[nt] = u.v;
            }
#pragma unroll
            for (int mt=0;mt<2;mt++)
#pragma unroll
                for (int nt=0;nt<2;nt++)
                    acc[mt][nt] = __builtin_amdgcn_mfma_scale_f32_16x16x128_f8f6f4(
                        af[mt][kc], bfr[nt], acc[mt][nt],
                        0, 0,        // cbsz=FP8(e4m3), blgp=FP8(e4m3)
                        0, 127,      // scale_a opsel, scale_a (e8m0 1.0)
                        0, 127);     // scale_b opsel, scale_b
        }

        // S[row-slot] += sum_nt 2^((dot-1)*K2E)
#pragma unroll
        for (int mt=0;mt<2;mt++)
#pragma unroll
            for (int reg=0;reg<4;reg++){
                float e0 = exp2_fast(fmaf(acc[mt][0][reg], K2E, -K2E));
                float e1 = exp2_fast(fmaf(acc[mt][1][reg], K2E, -K2E));
                S[mt*4+reg] += e0 + e1;
            }
        __syncthreads();   // drains gll prefetch, publishes next buffer
    }

    // reduce over the 16 col-lanes (disjoint cols, same rows)
#pragma unroll
    for (int off=1; off<16; off<<=1)
#pragma unroll
        for (int s=0;s<8;s++) S[s] += __shfl_xor(S[s], off);

    if (c == 0){
        const int p = chnk*2 + wn;             // 16 partial slots
#pragma unroll
        for (int mt=0;mt<2;mt++)
#pragma unroll
            for (int reg=0;reg<4;reg++){
                int row = i0 + wm*32 + mt*16 + qq*4 + reg;
                Spart[p*BATCH + row] = S[mt*4+reg];
            }
    }
}

// ---------------------------------------------------------------------------
// K5: combine 16 partials/row -> LSE - diag, reduce to accs[1]; the LAST
// block (device-scope counter accs[2]) also writes the two output scalars.
// ---------------------------------------------------------------------------
__global__ __launch_bounds__(256) void
k_finalize(const float* __restrict__ Spart, const float* __restrict__ diag,
           float* __restrict__ accs, float* __restrict__ out_s) {
    int r = blockIdx.x*256 + threadIdx.x;
    float Ssum = 0.f;
#pragma unroll
    for (int p=0;p<16;p++) Ssum += Spart[p*BATCH + r];
    float val = INV_TAU + logf(Ssum) - diag[r];
    for (int off=32; off; off>>=1) val += __shfl_down(val, off);
    if ((threadIdx.x & 63)==0) atomicAdd(&accs[1], val);
    __syncthreads();                       // drains this block's atomics
    if (threadIdx.x == 0){
        __threadfence();
        unsigned int old = __float_as_uint(atomicAdd(&accs[2], 1.0f));
        if (old == __float_as_uint(31.0f)) {   // 32nd (last) block
            __threadfence();
            float a0 = atomicAdd(&accs[0], 0.0f);
            float a1 = atomicAdd(&accs[1], 0.0f);
            out_s[0] = 2.0f*a0 / (float)((size_t)BATCH*LDIM);   // commit+embed
            out_s[1] = a1 / (float)BATCH;                       // contrastive
        }
    }
}

// ---------------------------------------------------------------------------
extern "C" void kernel_launch(void* const* d_in, const int* in_sizes, int n_in,
                              void* d_out, int out_size, void* d_ws, size_t ws_size,
                              hipStream_t stream) {
    const float* z   = (const float*)d_in[0];   // (B, L)
    const float* emb = (const float*)d_in[1];   // (NC, K, SD)
    float* out = (float*)d_out;
    float* out_q       = out;                   // B*L = 4194304
    float* out_scalars = out + 4194304;         // [commit, contrastive]
    float* out_idx     = out + 4194306;         // B*NC as float

    // ws layout (float offsets); ~11 MB total
    float* wsf   = (float*)d_ws;
    float* e2    = wsf;                         // 8192
    float* accs  = wsf + 8192;                  // [commit, contrastive, counter]
    float* diag  = wsf + 8704;                  // 8192
    float* Spart = wsf + 16896;                 // 16 slots used (32 reserved)
    unsigned char* qn8 = (unsigned char*)(Spart + 32*BATCH);   // B*L fp8 (4 MB)
    unsigned char* zn8 = qn8 + (size_t)BATCH*LDIM;             // B*L fp8 (4 MB)
    unsigned short* eh = (unsigned short*)(zn8 + (size_t)BATCH*LDIM); // NC*K*SD bf16
    unsigned short* el = eh + (size_t)NCB*KC*SDIM;             // NC*K*SD bf16

    k_pre    <<<32,          256, 0, stream>>>(emb, e2, eh, el, accs);
    k_argmin <<<dim3(64,8),  256, 0, stream>>>(eh, el, e2, z, emb,
                                               out_q, out_idx, accs);
    k_norm   <<<BATCH,       256, 0, stream>>>(z, out_q, zn8, qn8, diag);
    k_logits <<<dim3(64,8),  512, 0, stream>>>(qn8, zn8, Spart);
    k_finalize<<<32,         256, 0, stream>>>(Spart, diag, accs, out_scalars);
}

// Round 5
// 171.467 us; speedup vs baseline: 1.2585x; 1.0747x over previous
//
#include <hip/hip_runtime.h>
#include <cstdint>
#include <cstddef>

// Problem constants
#define NCB   8
#define KC    1024
#define SDIM  64
#define LDIM  512          // NCB*SDIM
#define BATCH 8192
#define INV_TAU (1.0f/0.07f)
#define K2E  20.60992915555662f   // log2(e)/TAU
#define DBIAS 256.0f           // dist bias: dist+256 in [174,466) -> positive, 2 binades

typedef __bf16 bf16_t;
typedef bf16_t bf16x8 __attribute__((ext_vector_type(8)));
typedef float  floatx4 __attribute__((ext_vector_type(4)));
typedef int    intx8  __attribute__((ext_vector_type(8)));
typedef unsigned int u32;

__device__ __forceinline__ unsigned short f2bf(float f) {
    union { float f; unsigned int u; } c; c.f = f;
    unsigned int u = c.u;
    u += 0x7fffu + ((u >> 16) & 1u);   // round-to-nearest-even
    return (unsigned short)(u >> 16);
}
__device__ __forceinline__ float bf2f(unsigned short h) {
    union { unsigned int u; float f; } c; c.u = ((unsigned int)h) << 16;
    return c.f;
}
__device__ __forceinline__ float exp2_fast(float x) {
    float r; asm("v_exp_f32 %0, %1" : "=v"(r) : "v"(x)); return r;
}
// async global->LDS DMA, 16B/lane. LDS dest = wave-uniform base + lane*16 (linear).
__device__ __forceinline__ void gll16(const void* g, void* l) {
    __builtin_amdgcn_global_load_lds(
        (const __attribute__((address_space(1))) u32*)g,
        (__attribute__((address_space(3))) u32*)l,
        16, 0, 0);
}

// ---------------------------------------------------------------------------
// K0: embeddings: e2 + bf16 hi/lo split + zero accs. R18: 256 blocks,
// 8 lanes per row (was 32 blocks w/ serial 16-load chain per thread).
// ---------------------------------------------------------------------------
__global__ __launch_bounds__(256) void
k_pre(const float* __restrict__ emb, float* __restrict__ e2,
      unsigned short* __restrict__ eh, unsigned short* __restrict__ el,
      float* __restrict__ accs) {
    int gid = blockIdx.x * 256 + threadIdx.x;   // 0..65535
    int row = gid >> 3, g = gid & 7;            // row 0..8191, 8 floats/lane
    const float4* e4 = (const float4*)(emb + (size_t)row*SDIM + g*8);
    float4 a = e4[0], b = e4[1];
    union { ushort4 u4[2]; uint4 v; } H, L;
    H.u4[0].x=f2bf(a.x); L.u4[0].x=f2bf(a.x-bf2f(H.u4[0].x));
    H.u4[0].y=f2bf(a.y); L.u4[0].y=f2bf(a.y-bf2f(H.u4[0].y));
    H.u4[0].z=f2bf(a.z); L.u4[0].z=f2bf(a.z-bf2f(H.u4[0].z));
    H.u4[0].w=f2bf(a.w); L.u4[0].w=f2bf(a.w-bf2f(H.u4[0].w));
    H.u4[1].x=f2bf(b.x); L.u4[1].x=f2bf(b.x-bf2f(H.u4[1].x));
    H.u4[1].y=f2bf(b.y); L.u4[1].y=f2bf(b.y-bf2f(H.u4[1].y));
    H.u4[1].z=f2bf(b.z); L.u4[1].z=f2bf(b.z-bf2f(H.u4[1].z));
    H.u4[1].w=f2bf(b.w); L.u4[1].w=f2bf(b.w-bf2f(H.u4[1].w));
    *(uint4*)(eh + (size_t)row*SDIM + g*8) = H.v;
    *(uint4*)(el + (size_t)row*SDIM + g*8) = L.v;
    float s = a.x*a.x + a.y*a.y + a.z*a.z + a.w*a.w
            + b.x*b.x + b.y*b.y + b.z*b.z + b.w*b.w;
    s += __shfl_xor(s, 1); s += __shfl_xor(s, 2); s += __shfl_xor(s, 4);
    if (g == 0) e2[row] = s;
    if (gid == 0){ accs[0]=0.f; accs[1]=0.f; accs[2]=0.f; }
}

// fp64 "relative distance" e2 - 2*z.e (z2 cancels in argmin ordering)
__device__ __forceinline__ double dist64d(const float* __restrict__ e,
                                          const float* __restrict__ zg) {
    double se=0.0, sz=0.0;
#pragma unroll 8
    for (int i=0;i<64;i++){ double ev=(double)e[i];
        se = fma(ev,ev,se); sz = fma(ev,(double)zg[i],sz); }
    return se - 2.0*sz;
}

// ---------------------------------------------------------------------------
// K2: MFMA argmin. R18: R1-verified structure (A in LDS swizzled, B gll
// dbuf w/ pre-swizzled source, 1 barrier/jt, med3 top-2) with B tile
// shrunk 64->32 codes: LDS 65->51.5 KB => 3 blocks/CU (launch_bounds 256,3).
// R4 lesson: reg-resident A gets rematerialized by the allocator — A stays
// in LDS; occupancy comes from the LDS diet instead.
// ---------------------------------------------------------------------------
__global__ __launch_bounds__(256,3) void
k_argmin(const unsigned short* __restrict__ eh, const unsigned short* __restrict__ el,
         const float* __restrict__ e2, const float* __restrict__ z,
         const float* __restrict__ emb, float* __restrict__ out_q,
         float* __restrict__ out_idx, float* __restrict__ accs) {
    __shared__ __align__(16) unsigned short Ah[128*64], Al[128*64];
    __shared__ __align__(16) unsigned short Bh[2][32*64], Bl[2][32*64];
    __shared__ float e2s[2][32];
    __shared__ unsigned int mK[2][128][2];

    const int tid = threadIdx.x;
    const int n   = blockIdx.y;
    const int i0  = blockIdx.x * 128;
    const int wid = tid >> 6, lane = tid & 63;
    const int wm = wid & 1, wn = wid >> 1;
    const int c  = lane & 15, qq = lane >> 4;

    const unsigned char* ehb = (const unsigned char*)(eh + (size_t)n*KC*SDIM);
    const unsigned char* elb = (const unsigned char*)(el + (size_t)n*KC*SDIM);
    const float* e2n = e2 + n*KC;

    // gll lane geometry: 8 rows x 128B per wave-instr; source pre-swizzled
    const int brow = lane >> 3;                       // row-in-8
    const int bchk = ((lane & 7)*16) ^ (brow << 4);   // swizzled byte in row

    auto stageB = [&](int buf, int j0){
        int r0 = wid*8;                               // 4 waves x 8 rows = 32
        size_t go = (size_t)(j0 + r0 + brow)*128 + bchk;
        gll16(ehb + go, &Bh[buf][r0*64]);
        gll16(elb + go, &Bl[buf][r0*64]);
    };

    stageB(0, 0);   // async; drained by the pre-loop barrier
    if (tid < 32) e2s[0][tid] = e2n[tid] + DBIAS;

    // stage A (resident): read z fp32, split hi/lo in-kernel, swizzled store
#pragma unroll
    for (int s=0;s<8;s++){
        int seg = tid + s*256;           // 2048 segs; 16 float4-segs per row
        int r = seg >> 4, sg = seg & 15;
        float4 v = *(const float4*)(z + (size_t)(i0+r)*LDIM + n*SDIM + sg*4);
        ushort4 h, l;
        h.x=f2bf(v.x); l.x=f2bf(v.x-bf2f(h.x));
        h.y=f2bf(v.y); l.y=f2bf(v.y-bf2f(h.y));
        h.z=f2bf(v.z); l.z=f2bf(v.z-bf2f(h.z));
        h.w=f2bf(v.w); l.w=f2bf(v.w-bf2f(h.w));
        int off = r*64 + ((sg*4) ^ ((r&7)<<3));   // shorts; == byte XOR (r&7)<<4
        *(ushort4*)(&Ah[off]) = h;
        *(ushort4*)(&Al[off]) = l;
    }

    unsigned int k1[16], k2[16];
#pragma unroll
    for (int j=0;j<16;j++){ k1[j]=0xFFFFFFFFu; k2[j]=0xFFFFFFFFu; }

    __syncthreads();          // drains stageB(0) (implicit vmcnt0), publishes A

    for (int jt=0; jt<32; jt++){
        const int cur = jt & 1, nxt = cur ^ 1;
        const int j0 = jt*32;
        float e2r = 0.f;
        if (jt < 31){
            stageB(nxt, j0 + 32);                 // async prefetch next tile
            if (tid < 32) e2r = e2n[j0 + 32 + tid];
        }

        floatx4 acc[4];
#pragma unroll
        for (int mt=0;mt<4;mt++) acc[mt] = (floatx4){0.f,0.f,0.f,0.f};

#pragma unroll
        for (int t=0;t<2;t++){
            const int axo = (t*32 + qq*8) ^ ((c&7)<<3);   // shorts
            bf16x8 ah[4], alo[4], bh, bl;
            {
                int ro = (wn*16 + c)*64 + axo;     // B tile row 0..31
                bh = *(const bf16x8*)(&Bh[cur][ro]);
                bl = *(const bf16x8*)(&Bl[cur][ro]);
            }
#pragma unroll
            for (int mt=0;mt<4;mt++){
                int ro = (wm*64 + mt*16 + c)*64 + axo;
                ah[mt]  = *(const bf16x8*)(&Ah[ro]);
                alo[mt] = *(const bf16x8*)(&Al[ro]);
            }
#pragma unroll
            for (int mt=0;mt<4;mt++){
                acc[mt] = __builtin_amdgcn_mfma_f32_16x16x32_bf16(ah[mt],  bh, acc[mt], 0,0,0);
                acc[mt] = __builtin_amdgcn_mfma_f32_16x16x32_bf16(ah[mt],  bl, acc[mt], 0,0,0);
                acc[mt] = __builtin_amdgcn_mfma_f32_16x16x32_bf16(alo[mt], bh, acc[mt], 0,0,0);
            }
        }

        // biased dist -> packed key -> branchless top-2 (min + med3)
        {
            const int colb = wn*16 + c;
            float e2v = e2s[cur][colb];
            unsigned int kidx = (unsigned int)(j0 + colb);
#pragma unroll
            for (int mt=0;mt<4;mt++)
#pragma unroll
                for (int reg=0;reg<4;reg++){
                    float d = fmaf(-2.0f, acc[mt][reg], e2v);
                    unsigned int key = (__float_as_uint(d) & 0xFFFFFC00u) | kidx;
                    int s = mt*4+reg;
                    unsigned int o1 = k1[s], o2 = k2[s];
                    unsigned int nk2;
                    asm("v_med3_u32 %0, %1, %2, %3" : "=v"(nk2) : "v"(o1), "v"(o2), "v"(key));
                    k2[s] = nk2;                 // 2nd-smallest of {k1,k2,key}
                    k1[s] = min(o1, key);
                }
        }

        if (jt < 31 && tid < 32) e2s[nxt][tid] = e2r + DBIAS;
        __syncthreads();   // drains gll prefetch (vmcnt0), publishes buf nxt
    }

    // butterfly top-2 merge across the 16 col-lanes
#pragma unroll
    for (int off=1; off<16; off<<=1){
#pragma unroll
        for (int s=0;s<16;s++){
            unsigned int o1 = __shfl_xor(k1[s], off);
            unsigned int o2 = __shfl_xor(k2[s], off);
            unsigned int n1 = min(k1[s], o1);
            k2[s] = min( max(k1[s], o1), min(k2[s], o2) );
            k1[s] = n1;
        }
    }
    if (c == 0){
#pragma unroll
        for (int s=0;s<16;s++){
            int row = wm*64 + (s>>2)*16 + qq*4 + (s&3);
            mK[wn][row][0] = k1[s]; mK[wn][row][1] = k2[s];
        }
    }
    __syncthreads();

    if (tid < 128){
        int b = i0 + tid;
        unsigned int a1 = mK[0][tid][0], a2 = mK[0][tid][1];
        unsigned int c1 = mK[1][tid][0], c2 = mK[1][tid][1];
        unsigned int f1 = min(a1, c1);
        unsigned int f2 = min( max(a1, c1), min(a2, c2) );
        int ii1 = (int)(f1 & 0x3FFu);
        int ii2 = (int)(f2 & 0x3FFu);
        float d1q = __uint_as_float(f1 & 0xFFFFFC00u);
        float d2q = __uint_as_float(f2 & 0xFFFFFC00u);

        const float* eb = emb + (size_t)n*KC*SDIM;
        const float* zg = z + (size_t)b*LDIM + n*SDIM;
        if (d2q - d1q < 0.08f) {   // window covers quantization (0.031) + bf16 err
            double d1 = dist64d(eb + (size_t)ii1*SDIM, zg);
            double d2 = dist64d(eb + (size_t)ii2*SDIM, zg);
            if (d2 < d1 || (d2 == d1 && ii2 < ii1)) ii1 = ii2;
        }

        const float4* q4 = (const float4*)(eb + (size_t)ii1*SDIM);
        const float4* z4 = (const float4*)zg;
        float4* oq = (float4*)(out_q + (size_t)b*LDIM + n*SDIM);
        float cs = 0.f;
#pragma unroll
        for (int i=0;i<16;i++){
            float4 v = q4[i]; float4 zv = z4[i];
            oq[i] = v;
            float d0=v.x-zv.x, d1=v.y-zv.y, d2=v.z-zv.z, d3=v.w-zv.w;
            cs += d0*d0 + d1*d1 + d2*d2 + d3*d3;
        }
        out_idx[b*NCB + n] = (float)ii1;

        for (int off=32; off; off>>=1) cs += __shfl_down(cs, off);
        if ((tid & 63)==0) atomicAdd(&accs[0], cs);
    }
}

// ---------------------------------------------------------------------------
// K3: per-row L2 norms; write normalized FP8 (e4m3) copies + diag.
// R18: wave-per-row (4 rows/block), zero barriers, zero LDS, packed stores.
// ---------------------------------------------------------------------------
__global__ __launch_bounds__(256) void
k_norm(const float* __restrict__ z, const float* __restrict__ q,
       unsigned char* __restrict__ zn8, unsigned char* __restrict__ qn8,
       float* __restrict__ diag) {
    const int wid = threadIdx.x >> 6, lane = threadIdx.x & 63;
    const int b = blockIdx.x*4 + wid;
    const size_t base = (size_t)b*LDIM;
    const float4* z4 = (const float4*)(z + base + lane*8);
    const float4* q4 = (const float4*)(q + base + lane*8);
    float4 za = z4[0], zb = z4[1];
    float4 qa = q4[0], qb = q4[1];
    float sz = za.x*za.x + za.y*za.y + za.z*za.z + za.w*za.w
             + zb.x*zb.x + zb.y*zb.y + zb.z*zb.z + zb.w*zb.w;
    float sq = qa.x*qa.x + qa.y*qa.y + qa.z*qa.z + qa.w*qa.w
             + qb.x*qb.x + qb.y*qb.y + qb.z*qb.z + qb.w*qb.w;
    float sqz= qa.x*za.x + qa.y*za.y + qa.z*za.z + qa.w*za.w
             + qb.x*zb.x + qb.y*zb.y + qb.z*zb.z + qb.w*zb.w;
#pragma unroll
    for (int off=1; off<64; off<<=1){
        sz  += __shfl_xor(sz,  off);
        sq  += __shfl_xor(sq,  off);
        sqz += __shfl_xor(sqz, off);
    }
    float inz = 1.0f/fmaxf(sqrtf(sz), 1e-12f);
    float inq = 1.0f/fmaxf(sqrtf(sq), 1e-12f);
    if (lane == 0) diag[b] = sqz*inz*inq*INV_TAU;

    int z0 = __builtin_amdgcn_cvt_pk_fp8_f32(za.x*inz, za.y*inz, 0, false);
    z0     = __builtin_amdgcn_cvt_pk_fp8_f32(za.z*inz, za.w*inz, z0, true);
    int z1 = __builtin_amdgcn_cvt_pk_fp8_f32(zb.x*inz, zb.y*inz, 0, false);
    z1     = __builtin_amdgcn_cvt_pk_fp8_f32(zb.z*inz, zb.w*inz, z1, true);
    int q0 = __builtin_amdgcn_cvt_pk_fp8_f32(qa.x*inq, qa.y*inq, 0, false);
    q0     = __builtin_amdgcn_cvt_pk_fp8_f32(qa.z*inq, qa.w*inq, q0, true);
    int q1 = __builtin_amdgcn_cvt_pk_fp8_f32(qb.x*inq, qb.y*inq, 0, false);
    q1     = __builtin_amdgcn_cvt_pk_fp8_f32(qb.z*inq, qb.w*inq, q1, true);
    uint2 uz; uz.x = (unsigned)z0; uz.y = (unsigned)z1;
    uint2 uq; uq.x = (unsigned)q0; uq.y = (unsigned)q1;
    *(uint2*)(zn8 + base + lane*8) = uz;
    *(uint2*)(qn8 + base + lane*8) = uq;
}

// ---------------------------------------------------------------------------
// K4: logsumexp of logits = qn8 · zn8^T / TAU via MX-scaled fp8 MFMA
// 16x16x128 (scales=1.0). R18: 4 waves, each owns 32 rows -> af[2][4]
// = 64 VGPR, PINNED with opaque asm (R3/R4: allocator remats unprotected
// operand arrays). B in 32-col LDS dbuf (32 KB) staged by gll w/
// pre-swizzled source; 1 barrier/jt; launch_bounds(256,3) = 3 blocks/CU.
// Each block now covers its full 1024-col chunk per wave -> 8 Spart slots.
// ---------------------------------------------------------------------------
__global__ __launch_bounds__(256,3) void
k_logits(const unsigned char* __restrict__ qn8, const unsigned char* __restrict__ zn8,
         float* __restrict__ Spart) {
    __shared__ __align__(16) unsigned char Bs[2][32*512];
    const int tid  = threadIdx.x;
    const int i0   = blockIdx.x * 128;
    const int chnk = blockIdx.y;           // 1024 cols each
    const int wid  = tid >> 6, lane = tid & 63;
    const int wm = wid;                    // 4 m-groups of 32 rows
    const int c  = lane & 15, qq = lane >> 4;

    // gll lane geometry: 2 rows x 512B per wave-instr; source pre-swizzled
    const int brow  = lane >> 5;
    const int bchk0 = (lane & 31) * 16;

    auto stageB = [&](int buf, int j0){
#pragma unroll
        for (int s=0;s<4;s++){
            int r0  = wid*8 + s*2;
            int row = r0 + brow;
            gll16(zn8 + (size_t)(j0+row)*LDIM + (bchk0 ^ ((row&7)<<4)),
                  &Bs[buf][r0*512]);
        }
    };

    stageB(0, chnk*1024);   // async; drained by the pre-loop barrier

    // ---- A resident in regs: 2 mt x 4 kc fragments (rows i0+wm*32+mt*16+c)
    intx8 af[2][4];
#pragma unroll
    for (int mt=0;mt<2;mt++){
        const unsigned char* ap = qn8 + (size_t)(i0 + wm*32 + mt*16 + c)*LDIM + qq*32;
#pragma unroll
        for (int kc=0;kc<4;kc++){
            union { intx8 v; uint4 h[2]; } u;
            u.h[0] = *(const uint4*)(ap + kc*128);
            u.h[1] = *(const uint4*)(ap + kc*128 + 16);
            af[mt][kc] = u.v;
        }
    }
    // pin af: opaque def makes rematerialization impossible (R4 lesson)
#pragma unroll
    for (int mt=0;mt<2;mt++)
#pragma unroll
        for (int kc=0;kc<4;kc++)
            asm volatile("" : "+v"(af[mt][kc]));

    float S[8];
#pragma unroll
    for (int i=0;i<8;i++) S[i] = 0.f;

    __syncthreads();        // drains stageB(0), publishes buf 0

    for (int jt=0;jt<32;jt++){
        const int cur = jt & 1;
        const int j0 = chnk*1024 + jt*32;
        if (jt < 31) stageB(cur^1, j0 + 32);   // async prefetch next tile

        floatx4 acc[2][2];
#pragma unroll
        for (int mt=0;mt<2;mt++){
            acc[mt][0]=(floatx4){0.f,0.f,0.f,0.f};
            acc[mt][1]=(floatx4){0.f,0.f,0.f,0.f};
        }

#pragma unroll
        for (int kc=0;kc<4;kc++){
            intx8 bfr[2];
#pragma unroll
            for (int nt=0;nt<2;nt++){
                const int rb = nt*16 + c;          // tile row 0..31
                const unsigned char* p = &Bs[cur][rb*512];
                const int o = kc*128 + qq*32;
                const int x = (rb&7)<<4;
                union { intx8 v; uint4 h[2]; } u;
                u.h[0] = *(const uint4*)(p + (o ^ x));
                u.h[1] = *(const uint4*)(p + ((o + 16) ^ x));
                bfr[nt] = u.v;
            }
#pragma unroll
            for (int mt=0;mt<2;mt++)
#pragma unroll
                for (int nt=0;nt<2;nt++)
                    acc[mt][nt] = __builtin_amdgcn_mfma_scale_f32_16x16x128_f8f6f4(
                        af[mt][kc], bfr[nt], acc[mt][nt],
                        0, 0,        // cbsz=FP8(e4m3), blgp=FP8(e4m3)
                        0, 127,      // scale_a opsel, scale_a (e8m0 1.0)
                        0, 127);     // scale_b opsel, scale_b
        }

        // S[row-slot] += sum_nt 2^((dot-1)*K2E)
#pragma unroll
        for (int mt=0;mt<2;mt++)
#pragma unroll
            for (int reg=0;reg<4;reg++){
                float e0 = exp2_fast(fmaf(acc[mt][0][reg], K2E, -K2E));
                float e1 = exp2_fast(fmaf(acc[mt][1][reg], K2E, -K2E));
                S[mt*4+reg] += e0 + e1;
            }
        __syncthreads();   // drains gll prefetch, publishes next buffer
    }

    // reduce over the 16 col-lanes (disjoint cols, same rows)
#pragma unroll
    for (int off=1; off<16; off<<=1)
#pragma unroll
        for (int s=0;s<8;s++) S[s] += __shfl_xor(S[s], off);

    if (c == 0){
        const int p = chnk;                    // 8 partial slots
#pragma unroll
        for (int mt=0;mt<2;mt++)
#pragma unroll
            for (int reg=0;reg<4;reg++){
                int row = i0 + wm*32 + mt*16 + qq*4 + reg;
                Spart[p*BATCH + row] = S[mt*4+reg];
            }
    }
}

// ---------------------------------------------------------------------------
// K5: combine 8 partials/row -> LSE - diag, reduce to accs[1]; the LAST
// block (device-scope counter accs[2]) also writes the two output scalars.
// ---------------------------------------------------------------------------
__global__ __launch_bounds__(256) void
k_finalize(const float* __restrict__ Spart, const float* __restrict__ diag,
           float* __restrict__ accs, float* __restrict__ out_s) {
    int r = blockIdx.x*256 + threadIdx.x;
    float Ssum = 0.f;
#pragma unroll
    for (int p=0;p<8;p++) Ssum += Spart[p*BATCH + r];
    float val = INV_TAU + logf(Ssum) - diag[r];
    for (int off=32; off; off>>=1) val += __shfl_down(val, off);
    if ((threadIdx.x & 63)==0) atomicAdd(&accs[1], val);
    __syncthreads();                       // drains this block's atomics
    if (threadIdx.x == 0){
        __threadfence();
        unsigned int old = __float_as_uint(atomicAdd(&accs[2], 1.0f));
        if (old == __float_as_uint(31.0f)) {   // 32nd (last) block
            __threadfence();
            float a0 = atomicAdd(&accs[0], 0.0f);
            float a1 = atomicAdd(&accs[1], 0.0f);
            out_s[0] = 2.0f*a0 / (float)((size_t)BATCH*LDIM);   // commit+embed
            out_s[1] = a1 / (float)BATCH;                       // contrastive
        }
    }
}

// ---------------------------------------------------------------------------
extern "C" void kernel_launch(void* const* d_in, const int* in_sizes, int n_in,
                              void* d_out, int out_size, void* d_ws, size_t ws_size,
                              hipStream_t stream) {
    const float* z   = (const float*)d_in[0];   // (B, L)
    const float* emb = (const float*)d_in[1];   // (NC, K, SD)
    float* out = (float*)d_out;
    float* out_q       = out;                   // B*L = 4194304
    float* out_scalars = out + 4194304;         // [commit, contrastive]
    float* out_idx     = out + 4194306;         // B*NC as float

    // ws layout (float offsets); ~11 MB total
    float* wsf   = (float*)d_ws;
    float* e2    = wsf;                         // 8192
    float* accs  = wsf + 8192;                  // [commit, contrastive, counter]
    float* diag  = wsf + 8704;                  // 8192
    float* Spart = wsf + 16896;                 // 8 slots used (32 reserved)
    unsigned char* qn8 = (unsigned char*)(Spart + 32*BATCH);   // B*L fp8 (4 MB)
    unsigned char* zn8 = qn8 + (size_t)BATCH*LDIM;             // B*L fp8 (4 MB)
    unsigned short* eh = (unsigned short*)(zn8 + (size_t)BATCH*LDIM); // NC*K*SD bf16
    unsigned short* el = eh + (size_t)NCB*KC*SDIM;             // NC*K*SD bf16

    k_pre    <<<256,         256, 0, stream>>>(emb, e2, eh, el, accs);
    k_argmin <<<dim3(64,8),  256, 0, stream>>>(eh, el, e2, z, emb,
                                               out_q, out_idx, accs);
    k_norm   <<<2048,        256, 0, stream>>>(z, out_q, zn8, qn8, diag);
    k_logits <<<dim3(64,8),  256, 0, stream>>>(qn8, zn8, Spart);
    k_finalize<<<32,         256, 0, stream>>>(Spart, diag, accs, out_scalars);
}

// Round 6
// 158.844 us; speedup vs baseline: 1.3585x; 1.0795x over previous
//
#include <hip/hip_runtime.h>
#include <cstdint>
#include <cstddef>

// Problem constants
#define NCB   8
#define KC    1024
#define SDIM  64
#define LDIM  512          // NCB*SDIM
#define BATCH 8192
#define INV_TAU (1.0f/0.07f)
#define K2E  20.60992915555662f   // log2(e)/TAU
#define DBIAS 256.0f           // dist bias: dist+256 in [174,466) -> positive, 2 binades

typedef __bf16 bf16_t;
typedef bf16_t bf16x8 __attribute__((ext_vector_type(8)));
typedef float  floatx4 __attribute__((ext_vector_type(4)));
typedef int    intx8  __attribute__((ext_vector_type(8)));
typedef unsigned int u32;

__device__ __forceinline__ unsigned short f2bf(float f) {
    union { float f; unsigned int u; } c; c.f = f;
    unsigned int u = c.u;
    u += 0x7fffu + ((u >> 16) & 1u);   // round-to-nearest-even
    return (unsigned short)(u >> 16);
}
__device__ __forceinline__ float bf2f(unsigned short h) {
    union { unsigned int u; float f; } c; c.u = ((unsigned int)h) << 16;
    return c.f;
}
__device__ __forceinline__ float exp2_fast(float x) {
    float r; asm("v_exp_f32 %0, %1" : "=v"(r) : "v"(x)); return r;
}
// async global->LDS DMA, 16B/lane. LDS dest = wave-uniform base + lane*16 (linear).
__device__ __forceinline__ void gll16(const void* g, void* l) {
    __builtin_amdgcn_global_load_lds(
        (const __attribute__((address_space(1))) u32*)g,
        (__attribute__((address_space(3))) u32*)l,
        16, 0, 0);
}

// ---------------------------------------------------------------------------
// K0: embeddings: e2 + bf16 hi/lo split + zero accs. 256 blocks, 8 lanes/row.
// ---------------------------------------------------------------------------
__global__ __launch_bounds__(256) void
k_pre(const float* __restrict__ emb, float* __restrict__ e2,
      unsigned short* __restrict__ eh, unsigned short* __restrict__ el,
      float* __restrict__ accs) {
    int gid = blockIdx.x * 256 + threadIdx.x;   // 0..65535
    int row = gid >> 3, g = gid & 7;            // row 0..8191, 8 floats/lane
    const float4* e4 = (const float4*)(emb + (size_t)row*SDIM + g*8);
    float4 a = e4[0], b = e4[1];
    union { ushort4 u4[2]; uint4 v; } H, L;
    H.u4[0].x=f2bf(a.x); L.u4[0].x=f2bf(a.x-bf2f(H.u4[0].x));
    H.u4[0].y=f2bf(a.y); L.u4[0].y=f2bf(a.y-bf2f(H.u4[0].y));
    H.u4[0].z=f2bf(a.z); L.u4[0].z=f2bf(a.z-bf2f(H.u4[0].z));
    H.u4[0].w=f2bf(a.w); L.u4[0].w=f2bf(a.w-bf2f(H.u4[0].w));
    H.u4[1].x=f2bf(b.x); L.u4[1].x=f2bf(b.x-bf2f(H.u4[1].x));
    H.u4[1].y=f2bf(b.y); L.u4[1].y=f2bf(b.y-bf2f(H.u4[1].y));
    H.u4[1].z=f2bf(b.z); L.u4[1].z=f2bf(b.z-bf2f(H.u4[1].z));
    H.u4[1].w=f2bf(b.w); L.u4[1].w=f2bf(b.w-bf2f(H.u4[1].w));
    *(uint4*)(eh + (size_t)row*SDIM + g*8) = H.v;
    *(uint4*)(el + (size_t)row*SDIM + g*8) = L.v;
    float s = a.x*a.x + a.y*a.y + a.z*a.z + a.w*a.w
            + b.x*b.x + b.y*b.y + b.z*b.z + b.w*b.w;
    s += __shfl_xor(s, 1); s += __shfl_xor(s, 2); s += __shfl_xor(s, 4);
    if (g == 0) e2[row] = s;
    if (gid == 0){ accs[0]=0.f; accs[1]=0.f; accs[2]=0.f; }
}

// fp64 "relative distance" e2 - 2*z.e (z2 cancels in argmin ordering)
__device__ __forceinline__ double dist64d(const float* __restrict__ e,
                                          const float* __restrict__ zg) {
    double se=0.0, sz=0.0;
#pragma unroll 8
    for (int i=0;i<64;i++){ double ev=(double)e[i];
        se = fma(ev,ev,se); sz = fma(ev,(double)zg[i],sz); }
    return se - 2.0*sz;
}

// ---------------------------------------------------------------------------
// K2: MFMA argmin. R19 = R1-verified structure (A in LDS swizzled, B gll
// dbuf, 64-code tiles, 16 phases, med3 top-2) + XCD PINNING:
// XCD = linear_wgid % 8 = blockIdx.x & 7 (gridDim.x = 64). Mapping n to
// bx&7 puts all 64 blocks that share an n — and its 512 KB eh/el slice —
// on ONE XCD, so the per-phase gll stage hits L2 (~200cy) instead of
// thrash-missing to L3/HBM (~1000cy/phase, the R5-measured marginal
// barrier-phase cost).
// ---------------------------------------------------------------------------
__global__ __launch_bounds__(256,2) void
k_argmin(const unsigned short* __restrict__ eh, const unsigned short* __restrict__ el,
         const float* __restrict__ e2, const float* __restrict__ z,
         const float* __restrict__ emb, float* __restrict__ out_q,
         float* __restrict__ out_idx, float* __restrict__ accs) {
    __shared__ __align__(16) unsigned short Ah[128*64], Al[128*64];
    __shared__ __align__(16) unsigned short Bh[2][64*64], Bl[2][64*64];
    __shared__ float e2s[2][64];
    __shared__ unsigned int mK[2][128][2];

    const int tid = threadIdx.x;
    // XCD pin: n = bx&7 (== XCD id); row-tile from remaining bits.
    const int n   = blockIdx.x & 7;
    const int i0  = (((blockIdx.x >> 3) << 3) + blockIdx.y) * 128;
    const int wid = tid >> 6, lane = tid & 63;
    const int wm = wid & 1, wn = wid >> 1;
    const int c  = lane & 15, qq = lane >> 4;

    // stage A (resident): read z fp32, split hi/lo in-kernel, swizzled store
#pragma unroll
    for (int s=0;s<8;s++){
        int seg = tid + s*256;           // 2048 segs; 16 float4-segs per row
        int r = seg >> 4, sg = seg & 15;
        float4 v = *(const float4*)(z + (size_t)(i0+r)*LDIM + n*SDIM + sg*4);
        ushort4 h, l;
        h.x=f2bf(v.x); l.x=f2bf(v.x-bf2f(h.x));
        h.y=f2bf(v.y); l.y=f2bf(v.y-bf2f(h.y));
        h.z=f2bf(v.z); l.z=f2bf(v.z-bf2f(h.z));
        h.w=f2bf(v.w); l.w=f2bf(v.w-bf2f(h.w));
        int off = r*64 + ((sg*4) ^ ((r&7)<<3));   // shorts; == byte XOR (r&7)<<4
        *(ushort4*)(&Ah[off]) = h;
        *(ushort4*)(&Al[off]) = l;
    }

    const unsigned char* ehb = (const unsigned char*)(eh + (size_t)n*KC*SDIM);
    const unsigned char* elb = (const unsigned char*)(el + (size_t)n*KC*SDIM);
    const float* e2n = e2 + n*KC;

    // gll lane geometry: 8 rows x 128B per wave-instr; source pre-swizzled
    const int brow = lane >> 3;                       // row-in-8
    const int bchk = ((lane & 7)*16) ^ (brow << 4);   // swizzled byte in row

    auto stageB = [&](int buf, int j0){
#pragma unroll
        for (int s=0;s<2;s++){
            int r0 = wid*16 + s*8;                    // multiple of 8
            size_t go = (size_t)(j0 + r0 + brow)*128 + bchk;
            gll16(ehb + go, &Bh[buf][r0*64]);
            gll16(elb + go, &Bl[buf][r0*64]);
        }
    };

    if (tid < 64) e2s[0][tid] = e2n[tid] + DBIAS;
    stageB(0, 0);

    unsigned int k1[16], k2[16];
#pragma unroll
    for (int j=0;j<16;j++){ k1[j]=0xFFFFFFFFu; k2[j]=0xFFFFFFFFu; }

    __syncthreads();

    for (int jt=0; jt<16; jt++){
        const int cur = jt & 1, nxt = cur ^ 1;
        const int j0 = jt*64;
        float e2r = 0.f;
        if (jt < 15){
            stageB(nxt, j0 + 64);                 // async prefetch next tile
            if (tid < 64) e2r = e2n[j0 + 64 + tid];
        }

        floatx4 acc[4][2];
#pragma unroll
        for (int mt=0;mt<4;mt++){
            acc[mt][0]=(floatx4){0.f,0.f,0.f,0.f};
            acc[mt][1]=(floatx4){0.f,0.f,0.f,0.f};
        }

#pragma unroll
        for (int t=0;t<2;t++){
            const int axo = (t*32 + qq*8) ^ ((c&7)<<3);   // shorts
            bf16x8 ah[4], alo[4], bh[2], bl[2];
#pragma unroll
            for (int mt=0;mt<4;mt++){
                int ro = (wm*64 + mt*16 + c)*64 + axo;
                ah[mt]  = *(const bf16x8*)(&Ah[ro]);
                alo[mt] = *(const bf16x8*)(&Al[ro]);
            }
#pragma unroll
            for (int nt=0;nt<2;nt++){
                int ro = (wn*32 + nt*16 + c)*64 + axo;
                bh[nt] = *(const bf16x8*)(&Bh[cur][ro]);
                bl[nt] = *(const bf16x8*)(&Bl[cur][ro]);
            }
#pragma unroll
            for (int mt=0;mt<4;mt++)
#pragma unroll
                for (int nt=0;nt<2;nt++){
                    acc[mt][nt] = __builtin_amdgcn_mfma_f32_16x16x32_bf16(ah[mt],  bh[nt], acc[mt][nt], 0,0,0);
                    acc[mt][nt] = __builtin_amdgcn_mfma_f32_16x16x32_bf16(ah[mt],  bl[nt], acc[mt][nt], 0,0,0);
                    acc[mt][nt] = __builtin_amdgcn_mfma_f32_16x16x32_bf16(alo[mt], bh[nt], acc[mt][nt], 0,0,0);
                }
        }

        // biased dist -> packed key -> branchless top-2 (min + med3)
#pragma unroll
        for (int nt=0;nt<2;nt++){
            const int colb = wn*32 + nt*16 + c;
            float e2v = e2s[cur][colb];
            unsigned int kidx = (unsigned int)(j0 + colb);
#pragma unroll
            for (int mt=0;mt<4;mt++)
#pragma unroll
                for (int reg=0;reg<4;reg++){
                    float d = fmaf(-2.0f, acc[mt][nt][reg], e2v);
                    unsigned int key = (__float_as_uint(d) & 0xFFFFFC00u) | kidx;
                    int s = mt*4+reg;
                    unsigned int o1 = k1[s], o2 = k2[s];
                    unsigned int nk2;
                    asm("v_med3_u32 %0, %1, %2, %3" : "=v"(nk2) : "v"(o1), "v"(o2), "v"(key));
                    k2[s] = nk2;                 // 2nd-smallest of {k1,k2,key}
                    k1[s] = min(o1, key);
                }
        }

        if (jt < 15 && tid < 64) e2s[nxt][tid] = e2r + DBIAS;
        __syncthreads();   // drains gll prefetch (vmcnt0), publishes buf nxt
    }

    // butterfly top-2 merge across the 16 col-lanes
#pragma unroll
    for (int off=1; off<16; off<<=1){
#pragma unroll
        for (int s=0;s<16;s++){
            unsigned int o1 = __shfl_xor(k1[s], off);
            unsigned int o2 = __shfl_xor(k2[s], off);
            unsigned int n1 = min(k1[s], o1);
            k2[s] = min( max(k1[s], o1), min(k2[s], o2) );
            k1[s] = n1;
        }
    }
    if (c == 0){
#pragma unroll
        for (int s=0;s<16;s++){
            int row = wm*64 + (s>>2)*16 + qq*4 + (s&3);
            mK[wn][row][0] = k1[s]; mK[wn][row][1] = k2[s];
        }
    }
    __syncthreads();

    if (tid < 128){
        int b = i0 + tid;
        unsigned int a1 = mK[0][tid][0], a2 = mK[0][tid][1];
        unsigned int c1 = mK[1][tid][0], c2 = mK[1][tid][1];
        unsigned int f1 = min(a1, c1);
        unsigned int f2 = min( max(a1, c1), min(a2, c2) );
        int ii1 = (int)(f1 & 0x3FFu);
        int ii2 = (int)(f2 & 0x3FFu);
        float d1q = __uint_as_float(f1 & 0xFFFFFC00u);
        float d2q = __uint_as_float(f2 & 0xFFFFFC00u);

        const float* eb = emb + (size_t)n*KC*SDIM;
        const float* zg = z + (size_t)b*LDIM + n*SDIM;
        if (d2q - d1q < 0.08f) {   // window covers quantization (0.031) + bf16 err
            double d1 = dist64d(eb + (size_t)ii1*SDIM, zg);
            double d2 = dist64d(eb + (size_t)ii2*SDIM, zg);
            if (d2 < d1 || (d2 == d1 && ii2 < ii1)) ii1 = ii2;
        }

        const float4* q4 = (const float4*)(eb + (size_t)ii1*SDIM);
        const float4* z4 = (const float4*)zg;
        float4* oq = (float4*)(out_q + (size_t)b*LDIM + n*SDIM);
        float cs = 0.f;
#pragma unroll
        for (int i=0;i<16;i++){
            float4 v = q4[i]; float4 zv = z4[i];
            oq[i] = v;
            float d0=v.x-zv.x, d1=v.y-zv.y, d2=v.z-zv.z, d3=v.w-zv.w;
            cs += d0*d0 + d1*d1 + d2*d2 + d3*d3;
        }
        out_idx[b*NCB + n] = (float)ii1;

        for (int off=32; off; off>>=1) cs += __shfl_down(cs, off);
        if ((tid & 63)==0) atomicAdd(&accs[0], cs);
    }
}

// ---------------------------------------------------------------------------
// K3: per-row L2 norms; write normalized FP8 (e4m3) copies + diag.
// Wave-per-row (4 rows/block), zero barriers, zero LDS, packed stores.
// ---------------------------------------------------------------------------
__global__ __launch_bounds__(256) void
k_norm(const float* __restrict__ z, const float* __restrict__ q,
       unsigned char* __restrict__ zn8, unsigned char* __restrict__ qn8,
       float* __restrict__ diag) {
    const int wid = threadIdx.x >> 6, lane = threadIdx.x & 63;
    const int b = blockIdx.x*4 + wid;
    const size_t base = (size_t)b*LDIM;
    const float4* z4 = (const float4*)(z + base + lane*8);
    const float4* q4 = (const float4*)(q + base + lane*8);
    float4 za = z4[0], zb = z4[1];
    float4 qa = q4[0], qb = q4[1];
    float sz = za.x*za.x + za.y*za.y + za.z*za.z + za.w*za.w
             + zb.x*zb.x + zb.y*zb.y + zb.z*zb.z + zb.w*zb.w;
    float sq = qa.x*qa.x + qa.y*qa.y + qa.z*qa.z + qa.w*qa.w
             + qb.x*qb.x + qb.y*qb.y + qb.z*qb.z + qb.w*qb.w;
    float sqz= qa.x*za.x + qa.y*za.y + qa.z*za.z + qa.w*za.w
             + qb.x*zb.x + qb.y*zb.y + qb.z*zb.z + qb.w*zb.w;
#pragma unroll
    for (int off=1; off<64; off<<=1){
        sz  += __shfl_xor(sz,  off);
        sq  += __shfl_xor(sq,  off);
        sqz += __shfl_xor(sqz, off);
    }
    float inz = 1.0f/fmaxf(sqrtf(sz), 1e-12f);
    float inq = 1.0f/fmaxf(sqrtf(sq), 1e-12f);
    if (lane == 0) diag[b] = sqz*inz*inq*INV_TAU;

    int z0 = __builtin_amdgcn_cvt_pk_fp8_f32(za.x*inz, za.y*inz, 0, false);
    z0     = __builtin_amdgcn_cvt_pk_fp8_f32(za.z*inz, za.w*inz, z0, true);
    int z1 = __builtin_amdgcn_cvt_pk_fp8_f32(zb.x*inz, zb.y*inz, 0, false);
    z1     = __builtin_amdgcn_cvt_pk_fp8_f32(zb.z*inz, zb.w*inz, z1, true);
    int q0 = __builtin_amdgcn_cvt_pk_fp8_f32(qa.x*inq, qa.y*inq, 0, false);
    q0     = __builtin_amdgcn_cvt_pk_fp8_f32(qa.z*inq, qa.w*inq, q0, true);
    int q1 = __builtin_amdgcn_cvt_pk_fp8_f32(qb.x*inq, qb.y*inq, 0, false);
    q1     = __builtin_amdgcn_cvt_pk_fp8_f32(qb.z*inq, qb.w*inq, q1, true);
    uint2 uz; uz.x = (unsigned)z0; uz.y = (unsigned)z1;
    uint2 uq; uq.x = (unsigned)q0; uq.y = (unsigned)q1;
    *(uint2*)(zn8 + base + lane*8) = uz;
    *(uint2*)(qn8 + base + lane*8) = uq;
}

// ---------------------------------------------------------------------------
// K4: logsumexp of logits = qn8 · zn8^T / TAU via MX-scaled fp8 MFMA
// 16x16x128 (scales=1.0). R19: 512-col chunks -> grid (64,16) = 1024 blocks
// = 4 blocks/CU (real occupancy at last; LDS 33 KB, launch_bounds(256,4));
// XCD pin: chnk = (bx&7) + 8*(by&1) -> each XCD holds 2 B panels (512 KB)
// L2-resident. af[2][4]=64 VGPR asm-pinned (R4 remat lesson); nt-outer
// MFMA order keeps bfr at 8 VGPR so total ~120 fits the 128 cap.
// ---------------------------------------------------------------------------
__global__ __launch_bounds__(256,4) void
k_logits(const unsigned char* __restrict__ qn8, const unsigned char* __restrict__ zn8,
         float* __restrict__ Spart) {
    __shared__ __align__(16) unsigned char Bs[2][32*512];
    const int tid  = threadIdx.x;
    // XCD pin: chnk from bx&7 (XCD id) + one by bit; row-tile from the rest.
    const int chnk = (blockIdx.x & 7) + ((blockIdx.y & 1) << 3);   // 0..15, 512 cols
    const int i0   = (((blockIdx.x >> 3) << 3) + (blockIdx.y >> 1)) * 128;
    const int wid  = tid >> 6, lane = tid & 63;
    const int wm = wid;                    // 4 m-groups of 32 rows
    const int c  = lane & 15, qq = lane >> 4;

    // gll lane geometry: 2 rows x 512B per wave-instr; source pre-swizzled
    const int brow  = lane >> 5;
    const int bchk0 = (lane & 31) * 16;

    auto stageB = [&](int buf, int j0){
#pragma unroll
        for (int s=0;s<4;s++){
            int r0  = wid*8 + s*2;
            int row = r0 + brow;
            gll16(zn8 + (size_t)(j0+row)*LDIM + (bchk0 ^ ((row&7)<<4)),
                  &Bs[buf][r0*512]);
        }
    };

    stageB(0, chnk*512);   // async; drained by the pre-loop barrier

    // ---- A resident in regs: 2 mt x 4 kc fragments (rows i0+wm*32+mt*16+c)
    intx8 af[2][4];
#pragma unroll
    for (int mt=0;mt<2;mt++){
        const unsigned char* ap = qn8 + (size_t)(i0 + wm*32 + mt*16 + c)*LDIM + qq*32;
#pragma unroll
        for (int kc=0;kc<4;kc++){
            union { intx8 v; uint4 h[2]; } u;
            u.h[0] = *(const uint4*)(ap + kc*128);
            u.h[1] = *(const uint4*)(ap + kc*128 + 16);
            af[mt][kc] = u.v;
        }
    }
    // pin af: opaque def makes rematerialization impossible (R4 lesson)
#pragma unroll
    for (int mt=0;mt<2;mt++)
#pragma unroll
        for (int kc=0;kc<4;kc++)
            asm volatile("" : "+v"(af[mt][kc]));

    float S[8];
#pragma unroll
    for (int i=0;i<8;i++) S[i] = 0.f;

    __syncthreads();        // drains stageB(0), publishes buf 0

    for (int jt=0;jt<16;jt++){
        const int cur = jt & 1;
        const int j0 = chnk*512 + jt*32;
        if (jt < 15) stageB(cur^1, j0 + 32);   // async prefetch next tile

        floatx4 acc[2][2];
#pragma unroll
        for (int mt=0;mt<2;mt++){
            acc[mt][0]=(floatx4){0.f,0.f,0.f,0.f};
            acc[mt][1]=(floatx4){0.f,0.f,0.f,0.f};
        }

#pragma unroll
        for (int kc=0;kc<4;kc++)
#pragma unroll
            for (int nt=0;nt<2;nt++){
                const int rb = nt*16 + c;          // tile row 0..31
                const unsigned char* p = &Bs[cur][rb*512];
                const int o = kc*128 + qq*32;
                const int x = (rb&7)<<4;
                union { intx8 v; uint4 h[2]; } u;
                u.h[0] = *(const uint4*)(p + (o ^ x));
                u.h[1] = *(const uint4*)(p + ((o + 16) ^ x));
                intx8 bfr = u.v;
#pragma unroll
                for (int mt=0;mt<2;mt++)
                    acc[mt][nt] = __builtin_amdgcn_mfma_scale_f32_16x16x128_f8f6f4(
                        af[mt][kc], bfr, acc[mt][nt],
                        0, 0,        // cbsz=FP8(e4m3), blgp=FP8(e4m3)
                        0, 127,      // scale_a opsel, scale_a (e8m0 1.0)
                        0, 127);     // scale_b opsel, scale_b
            }

        // S[row-slot] += sum_nt 2^((dot-1)*K2E)
#pragma unroll
        for (int mt=0;mt<2;mt++)
#pragma unroll
            for (int reg=0;reg<4;reg++){
                float e0 = exp2_fast(fmaf(acc[mt][0][reg], K2E, -K2E));
                float e1 = exp2_fast(fmaf(acc[mt][1][reg], K2E, -K2E));
                S[mt*4+reg] += e0 + e1;
            }
        __syncthreads();   // drains gll prefetch, publishes next buffer
    }

    // reduce over the 16 col-lanes (disjoint cols, same rows)
#pragma unroll
    for (int off=1; off<16; off<<=1)
#pragma unroll
        for (int s=0;s<8;s++) S[s] += __shfl_xor(S[s], off);

    if (c == 0){
        const int p = chnk;                    // 16 partial slots
#pragma unroll
        for (int mt=0;mt<2;mt++)
#pragma unroll
            for (int reg=0;reg<4;reg++){
                int row = i0 + wm*32 + mt*16 + qq*4 + reg;
                Spart[p*BATCH + row] = S[mt*4+reg];
            }
    }
}

// ---------------------------------------------------------------------------
// K5: combine 16 partials/row -> LSE - diag, reduce to accs[1]; the LAST
// block (device-scope counter accs[2]) also writes the two output scalars.
// ---------------------------------------------------------------------------
__global__ __launch_bounds__(256) void
k_finalize(const float* __restrict__ Spart, const float* __restrict__ diag,
           float* __restrict__ accs, float* __restrict__ out_s) {
    int r = blockIdx.x*256 + threadIdx.x;
    float Ssum = 0.f;
#pragma unroll
    for (int p=0;p<16;p++) Ssum += Spart[p*BATCH + r];
    float val = INV_TAU + logf(Ssum) - diag[r];
    for (int off=32; off; off>>=1) val += __shfl_down(val, off);
    if ((threadIdx.x & 63)==0) atomicAdd(&accs[1], val);
    __syncthreads();                       // drains this block's atomics
    if (threadIdx.x == 0){
        __threadfence();
        unsigned int old = __float_as_uint(atomicAdd(&accs[2], 1.0f));
        if (old == __float_as_uint(31.0f)) {   // 32nd (last) block
            __threadfence();
            float a0 = atomicAdd(&accs[0], 0.0f);
            float a1 = atomicAdd(&accs[1], 0.0f);
            out_s[0] = 2.0f*a0 / (float)((size_t)BATCH*LDIM);   // commit+embed
            out_s[1] = a1 / (float)BATCH;                       // contrastive
        }
    }
}

// ---------------------------------------------------------------------------
extern "C" void kernel_launch(void* const* d_in, const int* in_sizes, int n_in,
                              void* d_out, int out_size, void* d_ws, size_t ws_size,
                              hipStream_t stream) {
    const float* z   = (const float*)d_in[0];   // (B, L)
    const float* emb = (const float*)d_in[1];   // (NC, K, SD)
    float* out = (float*)d_out;
    float* out_q       = out;                   // B*L = 4194304
    float* out_scalars = out + 4194304;         // [commit, contrastive]
    float* out_idx     = out + 4194306;         // B*NC as float

    // ws layout (float offsets); ~11 MB total
    float* wsf   = (float*)d_ws;
    float* e2    = wsf;                         // 8192
    float* accs  = wsf + 8192;                  // [commit, contrastive, counter]
    float* diag  = wsf + 8704;                  // 8192
    float* Spart = wsf + 16896;                 // 16 slots used (32 reserved)
    unsigned char* qn8 = (unsigned char*)(Spart + 32*BATCH);   // B*L fp8 (4 MB)
    unsigned char* zn8 = qn8 + (size_t)BATCH*LDIM;             // B*L fp8 (4 MB)
    unsigned short* eh = (unsigned short*)(zn8 + (size_t)BATCH*LDIM); // NC*K*SD bf16
    unsigned short* el = eh + (size_t)NCB*KC*SDIM;             // NC*K*SD bf16

    k_pre    <<<256,         256, 0, stream>>>(emb, e2, eh, el, accs);
    k_argmin <<<dim3(64,8),  256, 0, stream>>>(eh, el, e2, z, emb,
                                               out_q, out_idx, accs);
    k_norm   <<<2048,        256, 0, stream>>>(z, out_q, zn8, qn8, diag);
    k_logits <<<dim3(64,16), 256, 0, stream>>>(qn8, zn8, Spart);
    k_finalize<<<32,         256, 0, stream>>>(Spart, diag, accs, out_scalars);
}